// Round 1
// baseline (267.011 us; speedup 1.0000x reference)
//
#include <hip/hip_runtime.h>
#include <hip/hip_bf16.h>

typedef __bf16 bf16x8 __attribute__((ext_vector_type(8)));
typedef float f32x4 __attribute__((ext_vector_type(4)));
typedef unsigned short u16x8 __attribute__((ext_vector_type(8)));

// B=128, T=256, D=512, H=8, HD=64. M = B*T = 32768.

__device__ __forceinline__ unsigned short f2bf(float f) {
  unsigned u = __float_as_uint(f);
  u += 0x7fffu + ((u >> 16) & 1u);   // RNE
  return (unsigned short)(u >> 16);
}

// ---------------- x fp32 -> bf16 ----------------
__global__ __launch_bounds__(256) void k_convert_x(const float* __restrict__ in,
                                                   unsigned short* __restrict__ out) {
  int i = blockIdx.x * 256 + threadIdx.x;      // 8192 blocks * 256 * 8 elems = 16.7M
  const float4* p = (const float4*)in + (size_t)i * 2;
  float4 a = p[0], b = p[1];
  u16x8 o;
  o[0] = f2bf(a.x); o[1] = f2bf(a.y); o[2] = f2bf(a.z); o[3] = f2bf(a.w);
  o[4] = f2bf(b.x); o[5] = f2bf(b.y); o[6] = f2bf(b.z); o[7] = f2bf(b.w);
  *((u16x8*)out + i) = o;
}

// ---------------- W fp32 [batch][rows][cols] -> bf16 [batch][cols][rows] ----------------
__global__ __launch_bounds__(256) void k_transpose_w(const float* __restrict__ in,
                                                     unsigned short* __restrict__ out,
                                                     int rows, int cols) {
  __shared__ unsigned short tile[64][72];
  int c0 = blockIdx.x * 64, r0 = blockIdx.y * 64;
  const float* inb = in + (size_t)blockIdx.z * rows * cols;
  unsigned short* outb = out + (size_t)blockIdx.z * rows * cols;
  int tid = threadIdx.x;
  int r = tid >> 2, cq = (tid & 3) * 16;
  const float* src = inb + (size_t)(r0 + r) * cols + c0 + cq;
#pragma unroll
  for (int i = 0; i < 16; i += 4) {
    float4 v = *(const float4*)(src + i);
    tile[r][cq + i + 0] = f2bf(v.x);
    tile[r][cq + i + 1] = f2bf(v.y);
    tile[r][cq + i + 2] = f2bf(v.z);
    tile[r][cq + i + 3] = f2bf(v.w);
  }
  __syncthreads();
  int cr = tid >> 2, rq = (tid & 3) * 16;
  u16x8 o0, o1;
#pragma unroll
  for (int i = 0; i < 8; ++i) o0[i] = tile[rq + i][cr];
#pragma unroll
  for (int i = 0; i < 8; ++i) o1[i] = tile[rq + 8 + i][cr];
  unsigned short* dst = outb + (size_t)(c0 + cr) * rows + r0 + rq;
  *(u16x8*)dst = o0;
  *(u16x8*)(dst + 8) = o1;
}

// ---------------- QKV projection ----------------
// grid (256 mtiles, 8 heads), block 256 (4 waves). Tile: 128 rows x 64 cols x {q,k,v}.
// Q,K out: [B,H,T,HD] bf16.  V out transposed: [B,H,HD,T] bf16.
__global__ __launch_bounds__(256) void k_qkv(
    const unsigned short* __restrict__ xb,    // [32768][512]
    const unsigned short* __restrict__ Wqt,   // [8][64][512]
    const unsigned short* __restrict__ Wkt,
    const unsigned short* __restrict__ Wvt,
    unsigned short* __restrict__ Qb,
    unsigned short* __restrict__ Kb,
    unsigned short* __restrict__ Vtb) {
  __shared__ unsigned short Xs[128][72];
  __shared__ unsigned short Ws[3][64][72];
  int m0 = blockIdx.x * 128;
  int h = blockIdx.y;
  int tid = threadIdx.x, wid = tid >> 6, lane = tid & 63, lr = lane & 15, lg = lane >> 4;
  const unsigned short* Wt[3] = {Wqt + h * 64 * 512, Wkt + h * 64 * 512, Wvt + h * 64 * 512};
  f32x4 acc[3][2][4];
#pragma unroll
  for (int z = 0; z < 3; ++z)
#pragma unroll
    for (int rt = 0; rt < 2; ++rt)
#pragma unroll
      for (int nt = 0; nt < 4; ++nt) acc[z][rt][nt] = (f32x4){0.f, 0.f, 0.f, 0.f};

  for (int kb = 0; kb < 8; ++kb) {
    {
      int row = tid >> 1, half = tid & 1;
      const int4* s = (const int4*)(xb + (size_t)(m0 + row) * 512 + kb * 64 + half * 32);
      int4* d = (int4*)&Xs[row][half * 32];
      d[0] = s[0]; d[1] = s[1]; d[2] = s[2]; d[3] = s[3];
      int wr = tid >> 2, wq = tid & 3;
#pragma unroll
      for (int z = 0; z < 3; ++z) {
        const int4* ws = (const int4*)(Wt[z] + (size_t)wr * 512 + kb * 64 + wq * 16);
        int4* wd = (int4*)&Ws[z][wr][wq * 16];
        wd[0] = ws[0]; wd[1] = ws[1];
      }
    }
    __syncthreads();
#pragma unroll
    for (int k32 = 0; k32 < 2; ++k32) {
      bf16x8 a0 = *(const bf16x8*)&Xs[wid * 32 + lr][k32 * 32 + lg * 8];
      bf16x8 a1 = *(const bf16x8*)&Xs[wid * 32 + 16 + lr][k32 * 32 + lg * 8];
#pragma unroll
      for (int z = 0; z < 3; ++z) {
#pragma unroll
        for (int nt = 0; nt < 4; ++nt) {
          bf16x8 b = *(const bf16x8*)&Ws[z][nt * 16 + lr][k32 * 32 + lg * 8];
          acc[z][0][nt] = __builtin_amdgcn_mfma_f32_16x16x32_bf16(a0, b, acc[z][0][nt], 0, 0, 0);
          acc[z][1][nt] = __builtin_amdgcn_mfma_f32_16x16x32_bf16(a1, b, acc[z][1][nt], 0, 0, 0);
        }
      }
    }
    __syncthreads();
  }
  // epilogue: Q, K natural layout
#pragma unroll
  for (int z = 0; z < 2; ++z) {
    unsigned short* outp = (z == 0) ? Qb : Kb;
#pragma unroll
    for (int rt = 0; rt < 2; ++rt) {
#pragma unroll
      for (int r = 0; r < 4; ++r) {
        int m = m0 + wid * 32 + rt * 16 + lg * 4 + r;
        int bb = m >> 8, t = m & 255;
        unsigned short* o = outp + ((size_t)(bb * 8 + h) * 256 + t) * 64;
#pragma unroll
        for (int nt = 0; nt < 4; ++nt) o[nt * 16 + lr] = f2bf(acc[z][rt][nt][r]);
      }
    }
  }
  // V: transpose through LDS (reuse Xs), write [B,H,HD,T]
#pragma unroll
  for (int rt = 0; rt < 2; ++rt)
#pragma unroll
    for (int nt = 0; nt < 4; ++nt)
#pragma unroll
      for (int r = 0; r < 4; ++r)
        Xs[wid * 32 + rt * 16 + lg * 4 + r][nt * 16 + lr] = f2bf(acc[2][rt][nt][r]);
  __syncthreads();
  {
    int hd = tid >> 2, qt = tid & 3;
    int bb = m0 >> 8, t0 = m0 & 255;
    unsigned short* dst = Vtb + ((size_t)(bb * 8 + h) * 64 + hd) * 256 + t0 + qt * 32;
#pragma unroll
    for (int j = 0; j < 4; ++j) {
      u16x8 o;
#pragma unroll
      for (int i = 0; i < 8; ++i) o[i] = Xs[qt * 32 + j * 8 + i][hd];
      *(u16x8*)(dst + j * 8) = o;
    }
  }
}

// ---------------- fused causal attention ----------------
// grid 1024 (= b*8+h), block 256 (4 waves). Wave handles 16-row chunks (interleaved).
__global__ __launch_bounds__(256) void k_attn(
    const unsigned short* __restrict__ Qb,
    const unsigned short* __restrict__ Kb,
    const unsigned short* __restrict__ Vtb,
    unsigned short* __restrict__ Ob) {  // [B,T,512] bf16 (concat heads)
  __shared__ unsigned short Ks[256][72];
  __shared__ unsigned short Vts[64][264];
  __shared__ unsigned short Ps[4][16][280];
  int bh = blockIdx.x;
  int tid = threadIdx.x, wid = tid >> 6, lane = tid & 63, lr = lane & 15, lg = lane >> 4;
  {
    const int4* s = (const int4*)(Kb + (size_t)bh * 16384 + tid * 64);
    int4* d = (int4*)&Ks[tid][0];
#pragma unroll
    for (int i = 0; i < 8; ++i) d[i] = s[i];
    int vr = tid >> 2, vq = tid & 3;
    const int4* vs = (const int4*)(Vtb + (size_t)bh * 16384 + vr * 256 + vq * 64);
    int4* vd = (int4*)&Vts[vr][vq * 64];
#pragma unroll
    for (int i = 0; i < 8; ++i) vd[i] = vs[i];
  }
  __syncthreads();
  int bb = bh >> 3, h = bh & 7;

  for (int c = 0; c < 4; ++c) {
    int ci = c * 4 + wid;      // chunk 0..15, interleaved across waves for causal balance
    int t0 = ci * 16;
    int ntV = ci + 1;          // tiles with any valid (s <= t) data
    int ntE = (ntV + 1) & ~1;  // rounded even for K=32 PV steps
    int nk32 = ntE >> 1;
    const unsigned short* qsrc = Qb + (size_t)bh * 16384 + (t0 + lr) * 64 + lg * 8;
    bf16x8 aq0 = *(const bf16x8*)qsrc;
    bf16x8 aq1 = *(const bf16x8*)(qsrc + 32);
    f32x4 acc[16];
#pragma unroll
    for (int nt = 0; nt < 16; ++nt)
      if (nt < ntE) acc[nt] = (f32x4){0.f, 0.f, 0.f, 0.f};
#pragma unroll
    for (int nt = 0; nt < 16; ++nt)
      if (nt < ntV) {
        bf16x8 b0 = *(const bf16x8*)&Ks[nt * 16 + lr][lg * 8];
        acc[nt] = __builtin_amdgcn_mfma_f32_16x16x32_bf16(aq0, b0, acc[nt], 0, 0, 0);
        bf16x8 b1 = *(const bf16x8*)&Ks[nt * 16 + lr][32 + lg * 8];
        acc[nt] = __builtin_amdgcn_mfma_f32_16x16x32_bf16(aq1, b1, acc[nt], 0, 0, 0);
      }
    // scale + causal mask + row max
    float mrow[4] = {-3.0e38f, -3.0e38f, -3.0e38f, -3.0e38f};
#pragma unroll
    for (int nt = 0; nt < 16; ++nt)
      if (nt < ntE) {
#pragma unroll
        for (int r = 0; r < 4; ++r) {
          float v = acc[nt][r] * 0.125f;
          if (nt * 16 + lr > t0 + lg * 4 + r) v = -1.0e30f;
          acc[nt][r] = v;
          mrow[r] = fmaxf(mrow[r], v);
        }
      }
#pragma unroll
    for (int r = 0; r < 4; ++r) {
      mrow[r] = fmaxf(mrow[r], __shfl_xor(mrow[r], 1));
      mrow[r] = fmaxf(mrow[r], __shfl_xor(mrow[r], 2));
      mrow[r] = fmaxf(mrow[r], __shfl_xor(mrow[r], 4));
      mrow[r] = fmaxf(mrow[r], __shfl_xor(mrow[r], 8));
    }
    float srow[4] = {0.f, 0.f, 0.f, 0.f};
#pragma unroll
    for (int nt = 0; nt < 16; ++nt)
      if (nt < ntE) {
#pragma unroll
        for (int r = 0; r < 4; ++r) {
          float p = __expf(acc[nt][r] - mrow[r]);
          srow[r] += p;
          Ps[wid][lg * 4 + r][nt * 16 + lr] = f2bf(p);
        }
      }
#pragma unroll
    for (int r = 0; r < 4; ++r) {
      srow[r] += __shfl_xor(srow[r], 1);
      srow[r] += __shfl_xor(srow[r], 2);
      srow[r] += __shfl_xor(srow[r], 4);
      srow[r] += __shfl_xor(srow[r], 8);
    }
    __threadfence_block();  // P writes -> P reads (same wave; order LDS)
    f32x4 aco[4];
#pragma unroll
    for (int vt = 0; vt < 4; ++vt) aco[vt] = (f32x4){0.f, 0.f, 0.f, 0.f};
#pragma unroll
    for (int k32 = 0; k32 < 8; ++k32)
      if (k32 < nk32) {
        bf16x8 pa = *(const bf16x8*)&Ps[wid][lr][k32 * 32 + lg * 8];
#pragma unroll
        for (int vt = 0; vt < 4; ++vt) {
          bf16x8 vb = *(const bf16x8*)&Vts[vt * 16 + lr][k32 * 32 + lg * 8];
          aco[vt] = __builtin_amdgcn_mfma_f32_16x16x32_bf16(pa, vb, aco[vt], 0, 0, 0);
        }
      }
#pragma unroll
    for (int r = 0; r < 4; ++r) {
      float inv = 1.0f / srow[r];
      unsigned short* o = Ob + ((size_t)(bb * 256 + t0 + lg * 4 + r)) * 512 + h * 64;
#pragma unroll
      for (int vt = 0; vt < 4; ++vt) o[vt * 16 + lr] = f2bf(aco[vt][r] * inv);
    }
  }
}

// ---------------- output projection + bias ----------------
__global__ __launch_bounds__(256) void k_oproj(
    const unsigned short* __restrict__ Ab,   // [32768][512] bf16
    const unsigned short* __restrict__ Wot,  // [512 e][512 d] bf16
    const float* __restrict__ bo,
    float* __restrict__ out) {
  __shared__ unsigned short Xs[128][72];
  __shared__ unsigned short Ws[64][72];
  int m0 = blockIdx.x * 128, n0 = blockIdx.y * 64;
  int tid = threadIdx.x, wid = tid >> 6, lane = tid & 63, lr = lane & 15, lg = lane >> 4;
  f32x4 acc[2][4];
#pragma unroll
  for (int rt = 0; rt < 2; ++rt)
#pragma unroll
    for (int nt = 0; nt < 4; ++nt) acc[rt][nt] = (f32x4){0.f, 0.f, 0.f, 0.f};
  for (int kb = 0; kb < 8; ++kb) {
    {
      int row = tid >> 1, half = tid & 1;
      const int4* s = (const int4*)(Ab + (size_t)(m0 + row) * 512 + kb * 64 + half * 32);
      int4* d = (int4*)&Xs[row][half * 32];
      d[0] = s[0]; d[1] = s[1]; d[2] = s[2]; d[3] = s[3];
      int wr = tid >> 2, wq = tid & 3;
      const int4* ws = (const int4*)(Wot + (size_t)(n0 + wr) * 512 + kb * 64 + wq * 16);
      int4* wd = (int4*)&Ws[wr][wq * 16];
      wd[0] = ws[0]; wd[1] = ws[1];
    }
    __syncthreads();
#pragma unroll
    for (int k32 = 0; k32 < 2; ++k32) {
      bf16x8 a0 = *(const bf16x8*)&Xs[wid * 32 + lr][k32 * 32 + lg * 8];
      bf16x8 a1 = *(const bf16x8*)&Xs[wid * 32 + 16 + lr][k32 * 32 + lg * 8];
#pragma unroll
      for (int nt = 0; nt < 4; ++nt) {
        bf16x8 b = *(const bf16x8*)&Ws[nt * 16 + lr][k32 * 32 + lg * 8];
        acc[0][nt] = __builtin_amdgcn_mfma_f32_16x16x32_bf16(a0, b, acc[0][nt], 0, 0, 0);
        acc[1][nt] = __builtin_amdgcn_mfma_f32_16x16x32_bf16(a1, b, acc[1][nt], 0, 0, 0);
      }
    }
    __syncthreads();
  }
#pragma unroll
  for (int rt = 0; rt < 2; ++rt) {
#pragma unroll
    for (int r = 0; r < 4; ++r) {
      int m = m0 + wid * 32 + rt * 16 + lg * 4 + r;
      float* o = out + (size_t)m * 512 + n0;
#pragma unroll
      for (int nt = 0; nt < 4; ++nt) o[nt * 16 + lr] = acc[rt][nt][r] + bo[n0 + nt * 16 + lr];
    }
  }
}

extern "C" void kernel_launch(void* const* d_in, const int* in_sizes, int n_in,
                              void* d_out, int out_size, void* d_ws, size_t ws_size,
                              hipStream_t stream) {
  (void)in_sizes; (void)n_in; (void)out_size; (void)ws_size;
  const float* x = (const float*)d_in[0];
  const float* Wq = (const float*)d_in[1];
  const float* Wk = (const float*)d_in[2];
  const float* Wv = (const float*)d_in[3];
  const float* Wo = (const float*)d_in[4];
  const float* bo = (const float*)d_in[5];
  float* out = (float*)d_out;
  char* ws = (char*)d_ws;
  const size_t MB = 1024 * 1024;
  unsigned short* Qb = (unsigned short*)(ws);             // 32 MB
  unsigned short* Kb = (unsigned short*)(ws + 32 * MB);   // 32 MB
  unsigned short* Vtb = (unsigned short*)(ws + 64 * MB);  // 32 MB
  unsigned short* xb = (unsigned short*)(ws + 96 * MB);   // 32 MB (reused as attn out)
  unsigned short* Wqt = (unsigned short*)(ws + 128 * MB);
  unsigned short* Wkt = Wqt + 262144;
  unsigned short* Wvt = Wkt + 262144;
  unsigned short* Wot = Wvt + 262144;

  hipLaunchKernelGGL(k_convert_x, dim3(8192), dim3(256), 0, stream, x, xb);
  hipLaunchKernelGGL(k_transpose_w, dim3(1, 8, 8), dim3(256), 0, stream, Wq, Wqt, 512, 64);
  hipLaunchKernelGGL(k_transpose_w, dim3(1, 8, 8), dim3(256), 0, stream, Wk, Wkt, 512, 64);
  hipLaunchKernelGGL(k_transpose_w, dim3(1, 8, 8), dim3(256), 0, stream, Wv, Wvt, 512, 64);
  hipLaunchKernelGGL(k_transpose_w, dim3(8, 8, 1), dim3(256), 0, stream, Wo, Wot, 512, 512);
  hipLaunchKernelGGL(k_qkv, dim3(256, 8), dim3(256), 0, stream, xb, Wqt, Wkt, Wvt, Qb, Kb, Vtb);
  hipLaunchKernelGGL(k_attn, dim3(1024), dim3(256), 0, stream, Qb, Kb, Vtb, xb);
  hipLaunchKernelGGL(k_oproj, dim3(256, 8), dim3(256), 0, stream, xb, Wot, bo, out);
}

// Round 2
// 241.315 us; speedup vs baseline: 1.1065x; 1.1065x over previous
//
#include <hip/hip_runtime.h>
#include <hip/hip_bf16.h>

typedef __bf16 bf16x8 __attribute__((ext_vector_type(8)));
typedef float f32x4 __attribute__((ext_vector_type(4)));
typedef unsigned short u16x8 __attribute__((ext_vector_type(8)));

// B=128, T=256, D=512, H=8, HD=64. M = B*T = 32768.

__device__ __forceinline__ unsigned short f2bf(float f) {
  unsigned u = __float_as_uint(f);
  u += 0x7fffu + ((u >> 16) & 1u);   // RNE
  return (unsigned short)(u >> 16);
}

// async global->LDS, 16B per lane. LDS dest must be wave-uniform; HW adds lane*16.
__device__ __forceinline__ void async16(const void* g, void* l) {
  __builtin_amdgcn_global_load_lds(
      (const __attribute__((address_space(1))) void*)g,
      (__attribute__((address_space(3))) void*)l, 16, 0, 0);
}

// ---------------- x fp32 -> bf16 ----------------
__global__ __launch_bounds__(256) void k_convert_x(const float* __restrict__ in,
                                                   unsigned short* __restrict__ out) {
  int i = blockIdx.x * 256 + threadIdx.x;
  const float4* p = (const float4*)in + (size_t)i * 2;
  float4 a = p[0], b = p[1];
  u16x8 o;
  o[0] = f2bf(a.x); o[1] = f2bf(a.y); o[2] = f2bf(a.z); o[3] = f2bf(a.w);
  o[4] = f2bf(b.x); o[5] = f2bf(b.y); o[6] = f2bf(b.z); o[7] = f2bf(b.w);
  *((u16x8*)out + i) = o;
}

// ---------------- W fp32 [batch][rows][cols] -> bf16 [batch][cols][rows] ----------------
__global__ __launch_bounds__(256) void k_transpose_w(const float* __restrict__ in,
                                                     unsigned short* __restrict__ out,
                                                     int rows, int cols) {
  __shared__ unsigned short tile[64][72];
  int c0 = blockIdx.x * 64, r0 = blockIdx.y * 64;
  const float* inb = in + (size_t)blockIdx.z * rows * cols;
  unsigned short* outb = out + (size_t)blockIdx.z * rows * cols;
  int tid = threadIdx.x;
  int r = tid >> 2, cq = (tid & 3) * 16;
  const float* src = inb + (size_t)(r0 + r) * cols + c0 + cq;
#pragma unroll
  for (int i = 0; i < 16; i += 4) {
    float4 v = *(const float4*)(src + i);
    tile[r][cq + i + 0] = f2bf(v.x);
    tile[r][cq + i + 1] = f2bf(v.y);
    tile[r][cq + i + 2] = f2bf(v.z);
    tile[r][cq + i + 3] = f2bf(v.w);
  }
  __syncthreads();
  int cr = tid >> 2, rq = (tid & 3) * 16;
  u16x8 o0, o1;
#pragma unroll
  for (int i = 0; i < 8; ++i) o0[i] = tile[rq + i][cr];
#pragma unroll
  for (int i = 0; i < 8; ++i) o1[i] = tile[rq + 8 + i][cr];
  unsigned short* dst = outb + (size_t)(c0 + cr) * rows + r0 + rq;
  *(u16x8*)dst = o0;
  *(u16x8*)(dst + 8) = o1;
}

// ---------------- QKV projection: [32768,512] x [1536,512]^T ----------------
// m97 structure: 128x128 tile, BK=64, 4 waves in 2x2, global_load_lds staging.
// grid (256, 12): by 0-3 -> Q, 4-7 -> K, 8-11 -> V(transposed out).
__global__ __launch_bounds__(256) void k_qkv(
    const unsigned short* __restrict__ xb,    // [32768][512]
    const unsigned short* __restrict__ Wt,    // [1536][512]  (z,h,hd major)
    unsigned short* __restrict__ Qb,          // [B,H,T,HD]
    unsigned short* __restrict__ Kb,          // [B,H,T,HD]
    unsigned short* __restrict__ Vtb) {       // [B,H,HD,T]
  __shared__ unsigned short smem[17408];      // As[128*64] | Bs[128*64]; reused as Vls[128*136]
  unsigned short* As = smem;
  unsigned short* Bs = smem + 8192;
  int m0 = blockIdx.x * 128, n0 = blockIdx.y * 128;
  int tid = threadIdx.x, wid = tid >> 6, lane = tid & 63, lr = lane & 15, lg = lane >> 4;
  int wm = wid >> 1, wn = wid & 1;
  f32x4 acc[4][4];
#pragma unroll
  for (int mi = 0; mi < 4; ++mi)
#pragma unroll
    for (int ni = 0; ni < 4; ++ni) acc[mi][ni] = (f32x4){0.f, 0.f, 0.f, 0.f};

  for (int kb = 0; kb < 8; ++kb) {
#pragma unroll
    for (int c = 0; c < 4; ++c) {
      int ch = (wid * 4 + c) * 64 + lane;   // 16B-chunk index in 128x64 tile
      int row = ch >> 3, k8 = ch & 7;
      async16(xb + (size_t)(m0 + row) * 512 + kb * 64 + k8 * 8, As + (wid * 4 + c) * 512);
      async16(Wt + (size_t)(n0 + row) * 512 + kb * 64 + k8 * 8, Bs + (wid * 4 + c) * 512);
    }
    __syncthreads();   // compiler emits vmcnt(0) drain before barrier
#pragma unroll
    for (int k32 = 0; k32 < 2; ++k32) {
      bf16x8 am[4], bn[4];
#pragma unroll
      for (int i = 0; i < 4; ++i) {
        am[i] = *(const bf16x8*)&As[(wm * 64 + i * 16 + lr) * 64 + k32 * 32 + lg * 8];
        bn[i] = *(const bf16x8*)&Bs[(wn * 64 + i * 16 + lr) * 64 + k32 * 32 + lg * 8];
      }
#pragma unroll
      for (int mi = 0; mi < 4; ++mi)
#pragma unroll
        for (int ni = 0; ni < 4; ++ni)
          acc[mi][ni] = __builtin_amdgcn_mfma_f32_16x16x32_bf16(am[mi], bn[ni], acc[mi][ni], 0, 0, 0);
    }
    __syncthreads();
  }

  int z = n0 >> 9;
  int bb = m0 >> 8, t0 = m0 & 255;
  if (z < 2) {
    unsigned short* outp = z ? Kb : Qb;
#pragma unroll
    for (int ni = 0; ni < 4; ++ni) {
      int n_g = (n0 & 511) + wn * 64 + ni * 16 + lr;
      int h = n_g >> 6, hd = n_g & 63;
      unsigned short* obase = outp + ((size_t)(bb * 8 + h) * 256) * 64 + hd;
#pragma unroll
      for (int mi = 0; mi < 4; ++mi) {
        int t = t0 + wm * 64 + mi * 16 + lg * 4;
#pragma unroll
        for (int r = 0; r < 4; ++r)
          obase[(size_t)(t + r) * 64] = f2bf(acc[mi][ni][r]);
      }
    }
  } else {
    // V: transpose 128x128 through LDS (stride 136 shorts = 272B, conflict-light)
    unsigned short* Vls = smem;
#pragma unroll
    for (int ni = 0; ni < 4; ++ni) {
      int n_l = wn * 64 + ni * 16 + lr;
#pragma unroll
      for (int mi = 0; mi < 4; ++mi) {
        int m_l = wm * 64 + mi * 16 + lg * 4;
#pragma unroll
        for (int r = 0; r < 4; ++r)
          Vls[n_l * 136 + m_l + r] = f2bf(acc[mi][ni][r]);
      }
    }
    __syncthreads();
    int vrow = tid >> 1, vhalf = tid & 1;
    int n_g = (n0 & 511) + vrow;
    int h = n_g >> 6, hd = n_g & 63;
    unsigned short* dst = Vtb + ((size_t)(bb * 8 + h) * 64 + hd) * 256 + t0 + vhalf * 64;
    const unsigned short* srcp = &Vls[vrow * 136 + vhalf * 64];
#pragma unroll
    for (int j = 0; j < 8; ++j)
      *(u16x8*)(dst + j * 8) = *(const u16x8*)(srcp + j * 8);
  }
}

// ---------------- fused causal attention ----------------
__global__ __launch_bounds__(256) void k_attn(
    const unsigned short* __restrict__ Qb,
    const unsigned short* __restrict__ Kb,
    const unsigned short* __restrict__ Vtb,
    unsigned short* __restrict__ Ob) {  // [B,T,512] bf16 (concat heads)
  __shared__ unsigned short Ks[256][72];
  __shared__ unsigned short Vts[64][264];
  __shared__ unsigned short Ps[4][16][280];
  int bh = blockIdx.x;
  int tid = threadIdx.x, wid = tid >> 6, lane = tid & 63, lr = lane & 15, lg = lane >> 4;
  {
    const int4* s = (const int4*)(Kb + (size_t)bh * 16384 + tid * 64);
    int4* d = (int4*)&Ks[tid][0];
#pragma unroll
    for (int i = 0; i < 8; ++i) d[i] = s[i];
    int vr = tid >> 2, vq = tid & 3;
    const int4* vs = (const int4*)(Vtb + (size_t)bh * 16384 + vr * 256 + vq * 64);
    int4* vd = (int4*)&Vts[vr][vq * 64];
#pragma unroll
    for (int i = 0; i < 8; ++i) vd[i] = vs[i];
  }
  __syncthreads();
  int bb = bh >> 3, h = bh & 7;

  for (int c = 0; c < 4; ++c) {
    int ci = c * 4 + wid;
    int t0 = ci * 16;
    int ntV = ci + 1;
    int ntE = (ntV + 1) & ~1;
    int nk32 = ntE >> 1;
    const unsigned short* qsrc = Qb + (size_t)bh * 16384 + (t0 + lr) * 64 + lg * 8;
    bf16x8 aq0 = *(const bf16x8*)qsrc;
    bf16x8 aq1 = *(const bf16x8*)(qsrc + 32);
    f32x4 acc[16];
#pragma unroll
    for (int nt = 0; nt < 16; ++nt)
      if (nt < ntE) acc[nt] = (f32x4){0.f, 0.f, 0.f, 0.f};
#pragma unroll
    for (int nt = 0; nt < 16; ++nt)
      if (nt < ntV) {
        bf16x8 b0 = *(const bf16x8*)&Ks[nt * 16 + lr][lg * 8];
        acc[nt] = __builtin_amdgcn_mfma_f32_16x16x32_bf16(aq0, b0, acc[nt], 0, 0, 0);
        bf16x8 b1 = *(const bf16x8*)&Ks[nt * 16 + lr][32 + lg * 8];
        acc[nt] = __builtin_amdgcn_mfma_f32_16x16x32_bf16(aq1, b1, acc[nt], 0, 0, 0);
      }
    float mrow[4] = {-3.0e38f, -3.0e38f, -3.0e38f, -3.0e38f};
#pragma unroll
    for (int nt = 0; nt < 16; ++nt)
      if (nt < ntE) {
#pragma unroll
        for (int r = 0; r < 4; ++r) {
          float v = acc[nt][r] * 0.125f;
          if (nt * 16 + lr > t0 + lg * 4 + r) v = -1.0e30f;
          acc[nt][r] = v;
          mrow[r] = fmaxf(mrow[r], v);
        }
      }
#pragma unroll
    for (int r = 0; r < 4; ++r) {
      mrow[r] = fmaxf(mrow[r], __shfl_xor(mrow[r], 1));
      mrow[r] = fmaxf(mrow[r], __shfl_xor(mrow[r], 2));
      mrow[r] = fmaxf(mrow[r], __shfl_xor(mrow[r], 4));
      mrow[r] = fmaxf(mrow[r], __shfl_xor(mrow[r], 8));
    }
    float srow[4] = {0.f, 0.f, 0.f, 0.f};
#pragma unroll
    for (int nt = 0; nt < 16; ++nt)
      if (nt < ntE) {
#pragma unroll
        for (int r = 0; r < 4; ++r) {
          float p = __expf(acc[nt][r] - mrow[r]);
          srow[r] += p;
          Ps[wid][lg * 4 + r][nt * 16 + lr] = f2bf(p);
        }
      }
#pragma unroll
    for (int r = 0; r < 4; ++r) {
      srow[r] += __shfl_xor(srow[r], 1);
      srow[r] += __shfl_xor(srow[r], 2);
      srow[r] += __shfl_xor(srow[r], 4);
      srow[r] += __shfl_xor(srow[r], 8);
    }
    __threadfence_block();
    f32x4 aco[4];
#pragma unroll
    for (int vt = 0; vt < 4; ++vt) aco[vt] = (f32x4){0.f, 0.f, 0.f, 0.f};
#pragma unroll
    for (int k32 = 0; k32 < 8; ++k32)
      if (k32 < nk32) {
        bf16x8 pa = *(const bf16x8*)&Ps[wid][lr][k32 * 32 + lg * 8];
#pragma unroll
        for (int vt = 0; vt < 4; ++vt) {
          bf16x8 vb = *(const bf16x8*)&Vts[vt * 16 + lr][k32 * 32 + lg * 8];
          aco[vt] = __builtin_amdgcn_mfma_f32_16x16x32_bf16(pa, vb, aco[vt], 0, 0, 0);
        }
      }
#pragma unroll
    for (int r = 0; r < 4; ++r) {
      float inv = 1.0f / srow[r];
      unsigned short* o = Ob + ((size_t)(bb * 256 + t0 + lg * 4 + r)) * 512 + h * 64;
#pragma unroll
      for (int vt = 0; vt < 4; ++vt) o[vt * 16 + lr] = f2bf(aco[vt][r] * inv);
    }
  }
}

// ---------------- output projection + bias (m97 structure) ----------------
__global__ __launch_bounds__(256) void k_oproj(
    const unsigned short* __restrict__ Ab,   // [32768][512] bf16
    const unsigned short* __restrict__ Wot,  // [512][512] bf16 (n-major)
    const float* __restrict__ bo,
    float* __restrict__ out) {
  __shared__ unsigned short smem[16384];
  unsigned short* As = smem;
  unsigned short* Bs = smem + 8192;
  int m0 = blockIdx.x * 128, n0 = blockIdx.y * 128;
  int tid = threadIdx.x, wid = tid >> 6, lane = tid & 63, lr = lane & 15, lg = lane >> 4;
  int wm = wid >> 1, wn = wid & 1;
  f32x4 acc[4][4];
#pragma unroll
  for (int mi = 0; mi < 4; ++mi)
#pragma unroll
    for (int ni = 0; ni < 4; ++ni) acc[mi][ni] = (f32x4){0.f, 0.f, 0.f, 0.f};

  for (int kb = 0; kb < 8; ++kb) {
#pragma unroll
    for (int c = 0; c < 4; ++c) {
      int ch = (wid * 4 + c) * 64 + lane;
      int row = ch >> 3, k8 = ch & 7;
      async16(Ab + (size_t)(m0 + row) * 512 + kb * 64 + k8 * 8, As + (wid * 4 + c) * 512);
      async16(Wot + (size_t)(n0 + row) * 512 + kb * 64 + k8 * 8, Bs + (wid * 4 + c) * 512);
    }
    __syncthreads();
#pragma unroll
    for (int k32 = 0; k32 < 2; ++k32) {
      bf16x8 am[4], bn[4];
#pragma unroll
      for (int i = 0; i < 4; ++i) {
        am[i] = *(const bf16x8*)&As[(wm * 64 + i * 16 + lr) * 64 + k32 * 32 + lg * 8];
        bn[i] = *(const bf16x8*)&Bs[(wn * 64 + i * 16 + lr) * 64 + k32 * 32 + lg * 8];
      }
#pragma unroll
      for (int mi = 0; mi < 4; ++mi)
#pragma unroll
        for (int ni = 0; ni < 4; ++ni)
          acc[mi][ni] = __builtin_amdgcn_mfma_f32_16x16x32_bf16(am[mi], bn[ni], acc[mi][ni], 0, 0, 0);
    }
    __syncthreads();
  }
#pragma unroll
  for (int ni = 0; ni < 4; ++ni) {
    int n_g = n0 + wn * 64 + ni * 16 + lr;
    float bias = bo[n_g];
#pragma unroll
    for (int mi = 0; mi < 4; ++mi) {
      int m_g = m0 + wm * 64 + mi * 16 + lg * 4;
#pragma unroll
      for (int r = 0; r < 4; ++r)
        out[(size_t)(m_g + r) * 512 + n_g] = acc[mi][ni][r] + bias;
    }
  }
}

extern "C" void kernel_launch(void* const* d_in, const int* in_sizes, int n_in,
                              void* d_out, int out_size, void* d_ws, size_t ws_size,
                              hipStream_t stream) {
  (void)in_sizes; (void)n_in; (void)out_size; (void)ws_size;
  const float* x = (const float*)d_in[0];
  const float* Wq = (const float*)d_in[1];
  const float* Wk = (const float*)d_in[2];
  const float* Wv = (const float*)d_in[3];
  const float* Wo = (const float*)d_in[4];
  const float* bo = (const float*)d_in[5];
  float* out = (float*)d_out;
  char* ws = (char*)d_ws;
  const size_t MB = 1024 * 1024;
  unsigned short* Qb = (unsigned short*)(ws);             // 32 MB
  unsigned short* Kb = (unsigned short*)(ws + 32 * MB);   // 32 MB
  unsigned short* Vtb = (unsigned short*)(ws + 64 * MB);  // 32 MB
  unsigned short* xb = (unsigned short*)(ws + 96 * MB);   // 32 MB (reused as attn out)
  unsigned short* Wqt = (unsigned short*)(ws + 128 * MB); // [1536][512] contiguous (q,k,v)
  unsigned short* Wkt = Wqt + 262144;
  unsigned short* Wvt = Wkt + 262144;
  unsigned short* Wot = Wvt + 262144;

  hipLaunchKernelGGL(k_convert_x, dim3(8192), dim3(256), 0, stream, x, xb);
  hipLaunchKernelGGL(k_transpose_w, dim3(1, 8, 8), dim3(256), 0, stream, Wq, Wqt, 512, 64);
  hipLaunchKernelGGL(k_transpose_w, dim3(1, 8, 8), dim3(256), 0, stream, Wk, Wkt, 512, 64);
  hipLaunchKernelGGL(k_transpose_w, dim3(1, 8, 8), dim3(256), 0, stream, Wv, Wvt, 512, 64);
  hipLaunchKernelGGL(k_transpose_w, dim3(8, 8, 1), dim3(256), 0, stream, Wo, Wot, 512, 512);
  hipLaunchKernelGGL(k_qkv, dim3(256, 12), dim3(256), 0, stream, xb, Wqt, Qb, Kb, Vtb);
  hipLaunchKernelGGL(k_attn, dim3(1024), dim3(256), 0, stream, Qb, Kb, Vtb, xb);
  hipLaunchKernelGGL(k_oproj, dim3(256, 4), dim3(256), 0, stream, xb, Wot, bo, out);
}

// Round 3
// 222.371 us; speedup vs baseline: 1.2007x; 1.0852x over previous
//
#include <hip/hip_runtime.h>
#include <hip/hip_bf16.h>

typedef __bf16 bf16x8 __attribute__((ext_vector_type(8)));
typedef float f32x4 __attribute__((ext_vector_type(4)));
typedef unsigned short u16x8 __attribute__((ext_vector_type(8)));
typedef unsigned short u16x4 __attribute__((ext_vector_type(4)));

// B=128, T=256, D=512, H=8, HD=64. M = B*T = 32768.

__device__ __forceinline__ unsigned short f2bf(float f) {
  unsigned u = __float_as_uint(f);
  u += 0x7fffu + ((u >> 16) & 1u);   // RNE
  return (unsigned short)(u >> 16);
}

// async global->LDS, 16B per lane. LDS dest wave-uniform; HW adds lane*16.
__device__ __forceinline__ void async16(const void* g, void* l) {
  __builtin_amdgcn_global_load_lds(
      (const __attribute__((address_space(1))) void*)g,
      (__attribute__((address_space(3))) void*)l, 16, 0, 0);
}

// ---------------- x fp32 -> bf16 ----------------
__global__ __launch_bounds__(256) void k_convert_x(const float* __restrict__ in,
                                                   unsigned short* __restrict__ out) {
  int i = blockIdx.x * 256 + threadIdx.x;
  const float4* p = (const float4*)in + (size_t)i * 2;
  float4 a = p[0], b = p[1];
  u16x8 o;
  o[0] = f2bf(a.x); o[1] = f2bf(a.y); o[2] = f2bf(a.z); o[3] = f2bf(a.w);
  o[4] = f2bf(b.x); o[5] = f2bf(b.y); o[6] = f2bf(b.z); o[7] = f2bf(b.w);
  *((u16x8*)out + i) = o;
}

// ---------------- W fp32 [batch][rows][cols] -> bf16 [batch][cols][rows] ----------------
__global__ __launch_bounds__(256) void k_transpose_w(const float* __restrict__ in,
                                                     unsigned short* __restrict__ out,
                                                     int rows, int cols) {
  __shared__ unsigned short tile[64][72];
  int c0 = blockIdx.x * 64, r0 = blockIdx.y * 64;
  const float* inb = in + (size_t)blockIdx.z * rows * cols;
  unsigned short* outb = out + (size_t)blockIdx.z * rows * cols;
  int tid = threadIdx.x;
  int r = tid >> 2, cq = (tid & 3) * 16;
  const float* src = inb + (size_t)(r0 + r) * cols + c0 + cq;
#pragma unroll
  for (int i = 0; i < 16; i += 4) {
    float4 v = *(const float4*)(src + i);
    tile[r][cq + i + 0] = f2bf(v.x);
    tile[r][cq + i + 1] = f2bf(v.y);
    tile[r][cq + i + 2] = f2bf(v.z);
    tile[r][cq + i + 3] = f2bf(v.w);
  }
  __syncthreads();
  int cr = tid >> 2, rq = (tid & 3) * 16;
  u16x8 o0, o1;
#pragma unroll
  for (int i = 0; i < 8; ++i) o0[i] = tile[rq + i][cr];
#pragma unroll
  for (int i = 0; i < 8; ++i) o1[i] = tile[rq + 8 + i][cr];
  unsigned short* dst = outb + (size_t)(c0 + cr) * rows + r0 + rq;
  *(u16x8*)dst = o0;
  *(u16x8*)(dst + 8) = o1;
}

// ---------------- 256x256x(K=512) 8-phase GEMM, C = A * Bmat^T ----------------
// 8 waves (2M x 4N), BK=64, 128 KiB LDS double-buffer, T2 swizzle, counted vmcnt.
// MODE 0: qkv  (A=[32768][512] x, Bmat=[1536][512] Wqkv^T; writes Q,K [B,H,T,HD], V^T [B,H,HD,T])
// MODE 1: oproj(A=[32768][512] attn-out, Bmat=[512][512] Wo^T; writes fp32 out + bias)
template <int MODE>
__global__ __launch_bounds__(512, 2) void k_gemm256(
    const unsigned short* __restrict__ A,
    const unsigned short* __restrict__ Bmat,
    unsigned short* __restrict__ Qb,
    unsigned short* __restrict__ Kb,
    unsigned short* __restrict__ Vtb,
    const float* __restrict__ bo,
    float* __restrict__ outf) {
  __shared__ unsigned short smem[65536];   // 128 KiB: 2 bufs x (A0|A1|B0|B1) x 16 KiB
  const int NT = (MODE == 0) ? 768 : 256;
  const int XCHUNK = NT / 8;
  int bid = blockIdx.x;
  int swz = (bid % 8) * XCHUNK + bid / 8;   // bijective (NT % 8 == 0)
  int mt = swz & 127, nt = swz >> 7;
  int m0 = mt * 256, n0 = nt * 256;
  int tid = threadIdx.x;
  int wid = tid >> 6, lane = tid & 63;
  int lr = lane & 15, lg = lane >> 4;
  int wm = wid >> 2, wn = wid & 3;

  // ---- staging: linear LDS dest, inverse-swizzled global source (rule 21) ----
  int srow = wid * 16 + (lane >> 3);          // row within 128-row half (j=0)
  int scs = (lane & 7) ^ (lane >> 3);         // swizzled 16B-chunk index
  auto stage_tile = [&](int kb, int buf) {
#pragma unroll
    for (int H = 0; H < 4; ++H) {
      const unsigned short* gb = (H < 2) ? (A + (size_t)(m0 + H * 128) * 512)
                                         : (Bmat + (size_t)(n0 + (H - 2) * 128) * 512);
#pragma unroll
      for (int j = 0; j < 2; ++j) {
        int row = srow + j * 8;
        async16(gb + (size_t)row * 512 + kb * 64 + scs * 8,
                smem + buf * 32768 + H * 8192 + (wid * 2 + j) * 512);
      }
    }
  };
  // ---- swizzled ds_read of a 16x32 fragment ----
  int xcol0 = ((0 * 64 + lg * 16) ^ ((lr & 7) * 16)) >> 1;   // k32=0, in shorts
  int xcol1 = ((1 * 64 + lg * 16) ^ ((lr & 7) * 16)) >> 1;   // k32=1
  auto lda = [&](int buf, int mi, int k32) -> bf16x8 {
    int off = buf * 32768 + wm * 8192 + (mi * 16 + lr) * 64 + (k32 ? xcol1 : xcol0);
    return *(const bf16x8*)&smem[off];
  };
  auto ldb = [&](int buf, int ni, int k32) -> bf16x8 {
    int n = wn * 64 + ni * 16 + lr;
    int off = buf * 32768 + 16384 + (n >> 7) * 8192 + (n & 127) * 64 + (k32 ? xcol1 : xcol0);
    return *(const bf16x8*)&smem[off];
  };

  f32x4 acc[8][4];
#pragma unroll
  for (int mi = 0; mi < 8; ++mi)
#pragma unroll
    for (int ni = 0; ni < 4; ++ni) acc[mi][ni] = (f32x4){0.f, 0.f, 0.f, 0.f};

  // prologue: tiles 0,1 in flight; wait tile0 (8 loads/thread each)
  stage_tile(0, 0);
  stage_tile(1, 1);
  asm volatile("s_waitcnt vmcnt(8)" ::: "memory");
  __builtin_amdgcn_s_barrier();
  asm volatile("" ::: "memory");

  bf16x8 a03[4][2], a47[4][2], b01[2][2], b23[2][2];
#pragma unroll
  for (int t = 0; t < 8; ++t) {
    int buf = t & 1;
    // ---- phase 0: read A m0-3 + B n0-1; MFMA m0-3 x n0-1 ----
#pragma unroll
    for (int mi = 0; mi < 4; ++mi) { a03[mi][0] = lda(buf, mi, 0); a03[mi][1] = lda(buf, mi, 1); }
#pragma unroll
    for (int ni = 0; ni < 2; ++ni) { b01[ni][0] = ldb(buf, ni, 0); b01[ni][1] = ldb(buf, ni, 1); }
    __builtin_amdgcn_s_setprio(1);
#pragma unroll
    for (int mi = 0; mi < 4; ++mi)
#pragma unroll
      for (int ni = 0; ni < 2; ++ni)
#pragma unroll
        for (int k = 0; k < 2; ++k)
          acc[mi][ni] = __builtin_amdgcn_mfma_f32_16x16x32_bf16(a03[mi][k], b01[ni][k], acc[mi][ni], 0, 0, 0);
    __builtin_amdgcn_s_setprio(0);
    asm volatile("" ::: "memory");
    __builtin_amdgcn_s_barrier();
    asm volatile("" ::: "memory");
    // ---- phase 1: read A m4-7; MFMA m4-7 x n0-1 ----
#pragma unroll
    for (int mi = 0; mi < 4; ++mi) { a47[mi][0] = lda(buf, mi + 4, 0); a47[mi][1] = lda(buf, mi + 4, 1); }
    __builtin_amdgcn_s_setprio(1);
#pragma unroll
    for (int mi = 0; mi < 4; ++mi)
#pragma unroll
      for (int ni = 0; ni < 2; ++ni)
#pragma unroll
        for (int k = 0; k < 2; ++k)
          acc[mi + 4][ni] = __builtin_amdgcn_mfma_f32_16x16x32_bf16(a47[mi][k], b01[ni][k], acc[mi + 4][ni], 0, 0, 0);
    __builtin_amdgcn_s_setprio(0);
    asm volatile("" ::: "memory");
    __builtin_amdgcn_s_barrier();
    asm volatile("" ::: "memory");
    // ---- phase 2: read B n2-3; MFMA m4-7 x n2-3 ----
#pragma unroll
    for (int ni = 0; ni < 2; ++ni) { b23[ni][0] = ldb(buf, ni + 2, 0); b23[ni][1] = ldb(buf, ni + 2, 1); }
    __builtin_amdgcn_s_setprio(1);
#pragma unroll
    for (int mi = 0; mi < 4; ++mi)
#pragma unroll
      for (int ni = 0; ni < 2; ++ni)
#pragma unroll
        for (int k = 0; k < 2; ++k)
          acc[mi + 4][ni + 2] = __builtin_amdgcn_mfma_f32_16x16x32_bf16(a47[mi][k], b23[ni][k], acc[mi + 4][ni + 2], 0, 0, 0);
    __builtin_amdgcn_s_setprio(0);
    asm volatile("" ::: "memory");
    __builtin_amdgcn_s_barrier();
    asm volatile("" ::: "memory");
    // ---- phase 3: stage tile t+2 into buf (its reads all completed by ph2); MFMA m0-3 x n2-3 ----
    if (t < 6) stage_tile(t + 2, buf);
    __builtin_amdgcn_s_setprio(1);
#pragma unroll
    for (int mi = 0; mi < 4; ++mi)
#pragma unroll
      for (int ni = 0; ni < 2; ++ni)
#pragma unroll
        for (int k = 0; k < 2; ++k)
          acc[mi][ni + 2] = __builtin_amdgcn_mfma_f32_16x16x32_bf16(a03[mi][k], b23[ni][k], acc[mi][ni + 2], 0, 0, 0);
    __builtin_amdgcn_s_setprio(0);
    // counted wait: tile t+1 (issued last iter) landed; tile t+2's 8 loads stay in flight
    if (t < 6)      asm volatile("s_waitcnt vmcnt(8)" ::: "memory");
    else if (t == 6) asm volatile("s_waitcnt vmcnt(0)" ::: "memory");
    asm volatile("" ::: "memory");
    __builtin_amdgcn_s_barrier();
    asm volatile("" ::: "memory");
  }

  // ---- epilogue (LDS reuse needs full drain + barrier) ----
  asm volatile("s_waitcnt vmcnt(0) lgkmcnt(0)" ::: "memory");
  __builtin_amdgcn_s_barrier();
  asm volatile("" ::: "memory");

  if (MODE == 1) {
#pragma unroll
    for (int ni = 0; ni < 4; ++ni) {
      int n = n0 + wn * 64 + ni * 16 + lr;
      float bias = bo[n];
#pragma unroll
      for (int mi = 0; mi < 8; ++mi) {
        int m = m0 + wm * 128 + mi * 16 + lg * 4;
#pragma unroll
        for (int r = 0; r < 4; ++r)
          outf[(size_t)(m + r) * 512 + n] = acc[mi][ni][r] + bias;
      }
    }
  } else {
    int z = n0 >> 9;                       // 0=Q 1=K 2=V
    int bb = mt;                           // BM=256 == T: one batch per m-tile
    int h = ((n0 >> 6) & 7) + wn;          // wave owns exactly one head (64 cols)
    if (z < 2) {
      unsigned short* outp = (z ? Kb : Qb) + (size_t)(bb * 8 + h) * 16384;
#pragma unroll
      for (int ni = 0; ni < 4; ++ni) {
        int hd = ni * 16 + lr;
#pragma unroll
        for (int mi = 0; mi < 8; ++mi) {
          int tq = wm * 128 + mi * 16 + lg * 4;
#pragma unroll
          for (int r = 0; r < 4; ++r)
            outp[(size_t)(tq + r) * 64 + hd] = f2bf(acc[mi][ni][r]);
        }
      }
    } else {
      // V: per-wave LDS transpose (private 16 KiB region), 16B stores to [B,H,HD,T]
      unsigned short* Vls = smem + wid * 8192;
      unsigned short* outp = Vtb + (size_t)(bb * 8 + h) * 16384;
#pragma unroll
      for (int ni = 0; ni < 4; ++ni) {
#pragma unroll
        for (int mi = 0; mi < 8; ++mi) {
          u16x4 v;
          v[0] = f2bf(acc[mi][ni][0]); v[1] = f2bf(acc[mi][ni][1]);
          v[2] = f2bf(acc[mi][ni][2]); v[3] = f2bf(acc[mi][ni][3]);
          *(u16x4*)&Vls[lr * 136 + mi * 16 + lg * 4] = v;
        }
        int hd = ni * 16 + (lane >> 2);
        int tq0 = wm * 128 + (lane & 3) * 32;
#pragma unroll
        for (int jj = 0; jj < 4; ++jj) {
          u16x8 v = *(const u16x8*)&Vls[(lane >> 2) * 136 + (lane & 3) * 32 + jj * 8];
          *(u16x8*)&outp[(size_t)hd * 256 + tq0 + jj * 8] = v;
        }
      }
    }
  }
}

// ---------------- fused causal attention (unchanged) ----------------
__global__ __launch_bounds__(256) void k_attn(
    const unsigned short* __restrict__ Qb,
    const unsigned short* __restrict__ Kb,
    const unsigned short* __restrict__ Vtb,
    unsigned short* __restrict__ Ob) {  // [B,T,512] bf16 (concat heads)
  __shared__ unsigned short Ks[256][72];
  __shared__ unsigned short Vts[64][264];
  __shared__ unsigned short Ps[4][16][280];
  int bh = blockIdx.x;
  int tid = threadIdx.x, wid = tid >> 6, lane = tid & 63, lr = lane & 15, lg = lane >> 4;
  {
    const int4* s = (const int4*)(Kb + (size_t)bh * 16384 + tid * 64);
    int4* d = (int4*)&Ks[tid][0];
#pragma unroll
    for (int i = 0; i < 8; ++i) d[i] = s[i];
    int vr = tid >> 2, vq = tid & 3;
    const int4* vs = (const int4*)(Vtb + (size_t)bh * 16384 + vr * 256 + vq * 64);
    int4* vd = (int4*)&Vts[vr][vq * 64];
#pragma unroll
    for (int i = 0; i < 8; ++i) vd[i] = vs[i];
  }
  __syncthreads();
  int bb = bh >> 3, h = bh & 7;

  for (int c = 0; c < 4; ++c) {
    int ci = c * 4 + wid;
    int t0 = ci * 16;
    int ntV = ci + 1;
    int ntE = (ntV + 1) & ~1;
    int nk32 = ntE >> 1;
    const unsigned short* qsrc = Qb + (size_t)bh * 16384 + (t0 + lr) * 64 + lg * 8;
    bf16x8 aq0 = *(const bf16x8*)qsrc;
    bf16x8 aq1 = *(const bf16x8*)(qsrc + 32);
    f32x4 acc[16];
#pragma unroll
    for (int nt = 0; nt < 16; ++nt)
      if (nt < ntE) acc[nt] = (f32x4){0.f, 0.f, 0.f, 0.f};
#pragma unroll
    for (int nt = 0; nt < 16; ++nt)
      if (nt < ntV) {
        bf16x8 b0 = *(const bf16x8*)&Ks[nt * 16 + lr][lg * 8];
        acc[nt] = __builtin_amdgcn_mfma_f32_16x16x32_bf16(aq0, b0, acc[nt], 0, 0, 0);
        bf16x8 b1 = *(const bf16x8*)&Ks[nt * 16 + lr][32 + lg * 8];
        acc[nt] = __builtin_amdgcn_mfma_f32_16x16x32_bf16(aq1, b1, acc[nt], 0, 0, 0);
      }
    float mrow[4] = {-3.0e38f, -3.0e38f, -3.0e38f, -3.0e38f};
#pragma unroll
    for (int nt = 0; nt < 16; ++nt)
      if (nt < ntE) {
#pragma unroll
        for (int r = 0; r < 4; ++r) {
          float v = acc[nt][r] * 0.125f;
          if (nt * 16 + lr > t0 + lg * 4 + r) v = -1.0e30f;
          acc[nt][r] = v;
          mrow[r] = fmaxf(mrow[r], v);
        }
      }
#pragma unroll
    for (int r = 0; r < 4; ++r) {
      mrow[r] = fmaxf(mrow[r], __shfl_xor(mrow[r], 1));
      mrow[r] = fmaxf(mrow[r], __shfl_xor(mrow[r], 2));
      mrow[r] = fmaxf(mrow[r], __shfl_xor(mrow[r], 4));
      mrow[r] = fmaxf(mrow[r], __shfl_xor(mrow[r], 8));
    }
    float srow[4] = {0.f, 0.f, 0.f, 0.f};
#pragma unroll
    for (int nt = 0; nt < 16; ++nt)
      if (nt < ntE) {
#pragma unroll
        for (int r = 0; r < 4; ++r) {
          float p = __expf(acc[nt][r] - mrow[r]);
          srow[r] += p;
          Ps[wid][lg * 4 + r][nt * 16 + lr] = f2bf(p);
        }
      }
#pragma unroll
    for (int r = 0; r < 4; ++r) {
      srow[r] += __shfl_xor(srow[r], 1);
      srow[r] += __shfl_xor(srow[r], 2);
      srow[r] += __shfl_xor(srow[r], 4);
      srow[r] += __shfl_xor(srow[r], 8);
    }
    __threadfence_block();
    f32x4 aco[4];
#pragma unroll
    for (int vt = 0; vt < 4; ++vt) aco[vt] = (f32x4){0.f, 0.f, 0.f, 0.f};
#pragma unroll
    for (int k32 = 0; k32 < 8; ++k32)
      if (k32 < nk32) {
        bf16x8 pa = *(const bf16x8*)&Ps[wid][lr][k32 * 32 + lg * 8];
#pragma unroll
        for (int vt = 0; vt < 4; ++vt) {
          bf16x8 vb = *(const bf16x8*)&Vts[vt * 16 + lr][k32 * 32 + lg * 8];
          aco[vt] = __builtin_amdgcn_mfma_f32_16x16x32_bf16(pa, vb, aco[vt], 0, 0, 0);
        }
      }
#pragma unroll
    for (int r = 0; r < 4; ++r) {
      float inv = 1.0f / srow[r];
      unsigned short* o = Ob + ((size_t)(bb * 256 + t0 + lg * 4 + r)) * 512 + h * 64;
#pragma unroll
      for (int vt = 0; vt < 4; ++vt) o[vt * 16 + lr] = f2bf(aco[vt][r] * inv);
    }
  }
}

extern "C" void kernel_launch(void* const* d_in, const int* in_sizes, int n_in,
                              void* d_out, int out_size, void* d_ws, size_t ws_size,
                              hipStream_t stream) {
  (void)in_sizes; (void)n_in; (void)out_size; (void)ws_size;
  const float* x = (const float*)d_in[0];
  const float* Wq = (const float*)d_in[1];
  const float* Wk = (const float*)d_in[2];
  const float* Wv = (const float*)d_in[3];
  const float* Wo = (const float*)d_in[4];
  const float* bo = (const float*)d_in[5];
  float* out = (float*)d_out;
  char* ws = (char*)d_ws;
  const size_t MB = 1024 * 1024;
  unsigned short* Qb = (unsigned short*)(ws);             // 32 MB
  unsigned short* Kb = (unsigned short*)(ws + 32 * MB);   // 32 MB
  unsigned short* Vtb = (unsigned short*)(ws + 64 * MB);  // 32 MB
  unsigned short* xb = (unsigned short*)(ws + 96 * MB);   // 32 MB (reused as attn out)
  unsigned short* Wqt = (unsigned short*)(ws + 128 * MB); // [1536][512] contiguous (q,k,v)
  unsigned short* Wkt = Wqt + 262144;
  unsigned short* Wvt = Wkt + 262144;
  unsigned short* Wot = Wvt + 262144;

  hipLaunchKernelGGL(k_convert_x, dim3(8192), dim3(256), 0, stream, x, xb);
  hipLaunchKernelGGL(k_transpose_w, dim3(1, 8, 8), dim3(256), 0, stream, Wq, Wqt, 512, 64);
  hipLaunchKernelGGL(k_transpose_w, dim3(1, 8, 8), dim3(256), 0, stream, Wk, Wkt, 512, 64);
  hipLaunchKernelGGL(k_transpose_w, dim3(1, 8, 8), dim3(256), 0, stream, Wv, Wvt, 512, 64);
  hipLaunchKernelGGL(k_transpose_w, dim3(8, 8, 1), dim3(256), 0, stream, Wo, Wot, 512, 512);
  hipLaunchKernelGGL((k_gemm256<0>), dim3(768), dim3(512), 0, stream,
                     xb, Wqt, Qb, Kb, Vtb, bo, out);
  hipLaunchKernelGGL(k_attn, dim3(1024), dim3(256), 0, stream, Qb, Kb, Vtb, xb);
  hipLaunchKernelGGL((k_gemm256<1>), dim3(256), dim3(512), 0, stream,
                     xb, Wot, Qb, Kb, Vtb, bo, out);
}